// Round 13
// baseline (259.514 us; speedup 1.0000x reference)
//
#include <hip/hip_runtime.h>
#include <hip/hip_bf16.h>

#define EMB 128

typedef __attribute__((ext_vector_type(8))) short short8;   // 8 bf16 (4 VGPRs)
typedef __attribute__((ext_vector_type(4))) float floatx4;  // MFMA C/D
typedef __attribute__((ext_vector_type(2))) float v2f;      // -> v_pk_fma_f32

// 26 valid (ok, di, ol) message combos: deltas = {1,2,-1,-2}, ol = ok+delta in [0,8)
static constexpr int OKv[26] = {0,0,1,1,1,2,2,2,2,3,3,3,3,4,4,4,4,5,5,5,5,6,6,6,7,7};
static constexpr int DIv[26] = {0,1,0,1,2,0,1,2,3,0,1,2,3,0,1,2,3,0,1,2,3,0,2,3,2,3};
static constexpr int OLv[26] = {1,2,2,3,0,3,4,1,0,4,5,2,1,5,6,3,2,6,7,4,3,7,5,4,6,5};

__device__ __forceinline__ v2f ldv2(const float* p) { return *(const v2f*)p; }

// round-to-nearest-even bf16 bits of x, kept in the TOP 16 bits (low 16 zero)
__device__ __forceinline__ unsigned bf16_rne_hi(float x) {
  unsigned u = __float_as_uint(x);
  return (u + 0x7FFFu + ((u >> 16) & 1u)) & 0xFFFF0000u;
}
// HW packed cvt: a -> low 16, b -> high 16 (v_cvt_pk_bf16_f32 on gfx950)
__device__ __forceinline__ unsigned cvt_pk_bf16(float a, float b) {
  __hip_bfloat162 h = __float22bfloat162_rn(make_float2(a, b));
  unsigned r; __builtin_memcpy(&r, &h, 4); return r;
}
// unpack a bf16 pair (lo16 = .x, hi16 = .y) to v2f
__device__ __forceinline__ v2f unpk(unsigned p) {
  v2f r;
  r.x = __uint_as_float(p << 16);
  r.y = __uint_as_float(p & 0xFFFF0000u);
  return r;
}

union FragU { unsigned u[4]; uint4 q; short8 v; };

// LOGICAL CHANNEL PERMUTATION (R9-verified): MFMA C physical position
// (u, n=lane&15) carries logical channel L(u,n) = 2*((u>>1)*16 + n) + (u&1).
// Wave wv computes u in {2wv, 2wv+1} -> lane (wv, m16) holds the ADJACENT
// logical pair c0 = 2*(wv*16+m16), c0+1. Only wfrag bakes the permutation.
//
// SESSION NOTE (R27, final throw): R26 (scalarize + e-batch) was NULL ->
// VALU issue count off the critical path. Proven levers: residency (R19:
// occ 19->27% = -6.5%) and in-wave two-root ILP (R24: -4%), but R24 paid
// VGPR 80->128 (the 4-wave/SIMD boundary), cutting residency 27->19%.
// This round keeps the stagger and shrinks persistent state: X2A/X2B
// stored as PACKED BF16 pairs (16 VGPR/root, was 32), e-batch dropped.
// Unpack-on-use = 2 VALU/operand, cheap vs the ~80% stall wall. Precision:
// A-operand already rounds acc->bf16 every layer at absmax 0.0; the
// residual carrier gets the same-order quantization (~2^-9/layer).
// GATES: VGPR <= 104 (ideally <=102 -> 5 waves/SIMD) else shave failed;
// absmax must still pass. Both pass + dur flat -> plateau, revert R24.
// Falsified: occupancy-floor attrs (R1/R6), LDS size/barrier scope (R7/R11),
// epilogue (R8/R9), bank conflicts (R11), B-prefetch-in-phase (R12), VALU
// width (R13), wave-PARALLEL widening (R14/R20), ea residency/LDS
// (R15/R19/R22/R23), asm-confounded sync (R18), addr scalarization +
// batched loads (R25/R26 null). Wins: bf16-A (R16, -17%), bf16-B (R17,
// -2%), bounds floor (R19, -6.5%), 1-barrier dbuf+B-hoist (R21, -3%),
// R22 (-4%), two-root in-wave stagger (R24, -4%).

// Fused prep, grid 53 x 512:
//  b 0..31  : lin32 row b (4-way f-split + LDS reduce)
//  b 32..51 : w_conv -> B-fragment bf16 pre-pack with permuted N (160 frags)
//  b 52     : out[g] = b_pred[0]
__global__ __launch_bounds__(512) void prep_kernel(
    const float* __restrict__ emb_x,
    const float* __restrict__ w_ti,
    const float* __restrict__ b_ti,
    const float* __restrict__ w_conv,
    const float* __restrict__ b_pred,
    float* __restrict__ lin32,
    uint4* __restrict__ wfrag,
    float* __restrict__ out) {
  const int b = blockIdx.x, tid = threadIdx.x;
  if (b < 32) {
    __shared__ float red[4][EMB];
    const int e = tid & 127, fh = tid >> 7;      // fh in [0,4)
    const float* xr = emb_x + b * EMB;
    float s = 0.f;
    #pragma unroll 8
    for (int f = fh * 32; f < fh * 32 + 32; ++f)
      s = fmaf(xr[f], w_ti[f * EMB + e], s);
    red[fh][e] = s;
    __syncthreads();
    if (fh == 0)
      lin32[b * EMB + e] =
          b_ti[e] + ((red[0][e] + red[1][e]) + (red[2][e] + red[3][e]));
  } else if (b < 52) {
    const int id   = (b - 32) * 512 + tid;   // 160 frags * 64 lanes = 10240
    const int lane = id & 63;
    const int f    = id >> 6;         // frag index: [l][kt][u]
    const int u    = f & 7;           // N-tile (physical)
    const int t    = (f >> 3) & 3;    // K-tile
    const int l    = f >> 5;          // layer
    const int q    = lane >> 4, n = lane & 15;
    const int cN   = 2 * ((u >> 1) * 16 + n) + (u & 1);   // logical out channel
    unsigned w[4] = {0u, 0u, 0u, 0u};
    #pragma unroll
    for (int j = 0; j < 8; ++j) {
      const int kk = t * 32 + q * 8 + j;    // logical in channel (canonical)
      const float val = w_conv[l * (EMB * EMB) + kk * EMB + cN];
      const unsigned bb = bf16_rne_hi(val);
      w[j >> 1] |= (j & 1) ? bb : (bb >> 16);
    }
    wfrag[id] = make_uint4(w[0], w[1], w[2], w[3]);
  } else {
    if (tid < 64) out[tid] = b_pred[0];
  }
}

// ---- per-root phase helpers (forceinline, all indexing compile-time) ----

// X2 packed: each entry = bf16 pair for channels (c0, c0+1).
__device__ __forceinline__ void tuple_init(
    int i, int ibase, int io,
    const int* __restrict__ x, const int* __restrict__ edge_attr,
    const int* __restrict__ tuplefeat,
    const float* __restrict__ emb_x, const float* __restrict__ emb_tf,
    const float* __restrict__ lin32,
    int c0, int q2, unsigned (&X2)[4][4], unsigned (&pk)[4])
{
  #pragma unroll
  for (int m = 0; m < 26; ++m) {
    const int kg = ibase + ((io + OKv[m]) & 63);
    const unsigned a = (unsigned)edge_attr[(kg << 2) + DIv[m]];
    pk[m >> 3] |= a << ((m & 7) * 4);
  }
  const int xi = x[i];
  const v2f xe = ldv2(emb_x + xi * EMB + c0);
  v2f lj[2];
  #pragma unroll
  for (int ps = 0; ps < 2; ++ps) {
    const int jn = ibase + ((io + 2 * q2 + ps) & 63);
    lj[ps] = ldv2(lin32 + x[jn] * EMB + c0);
  }
  #pragma unroll
  for (int mt = 0; mt < 4; ++mt) {
    const int ps = mt & 1, kb = (mt >> 1) * 4;
    const int t0 = (i * 8 + 2 * q2 + ps) << 3;
    const v2f xl = xe * lj[ps];
    #pragma unroll
    for (int r = 0; r < 4; ++r) {
      const int2 tf2 = *(const int2*)(tuplefeat + 2 * (t0 + kb + r));
      const int row = (c0 < 64) ? tf2.x : tf2.y;   // c0,c0+1 in same half
      const v2f tf = ldv2(emb_tf + row * 64 + (c0 & 63));
      const v2f v = xl * tf;
      X2[mt][r] = cvt_pk_bf16(v.x, v.y);
    }
  }
}

// pku: SGPR copies of the block-uniform attr words (SALU unpack, scalar
// ea base). Loads inline (R24 form — the R26 e-batch was null).
__device__ __forceinline__ void msg_pack(
    const unsigned (&X2)[4][4], const unsigned (&pku)[4],
    const float* __restrict__ emb_ea,
    int c0, int q2, int pc, unsigned* fbuf)
{
  v2f acc[2][8];   // [ps][k]
  #pragma unroll
  for (int ps = 0; ps < 2; ++ps)
    #pragma unroll
    for (int k = 0; k < 8; ++k) acc[ps][k] = (v2f){0.f, 0.f};
  #pragma unroll
  for (int m = 0; m < 26; ++m) {
    const int attr = (int)((pku[m >> 3] >> ((m & 7) * 4)) & 15u);  // SALU
    const v2f e = ldv2(emb_ea + attr * EMB + c0);
    const int ok = OKv[m], ol = OLv[m];
    const int mtb = 2 * (ol >> 2), rl = ol & 3;   // compile-time consts
    acc[0][ok] += unpk(X2[mtb + 0][rl]) * e;      // unpack + v_pk_fma_f32
    acc[1][ok] += unpk(X2[mtb + 1][rl]) * e;
  }
  #pragma unroll
  for (int ps = 0; ps < 2; ++ps)
    #pragma unroll
    for (int k = 0; k < 8; ++k) {
      const v2f a = acc[ps][k];
      const int row = (ps + 2 * (k >> 2)) * 16 + q2 * 4 + (k & 3);
      fbuf[row * 68 + pc] = cvt_pk_bf16(a.x, a.y);
    }
}

// wvu: SGPR wave index -> wfrag addressing is scalar-base.
__device__ __forceinline__ void mfma_resid(
    const unsigned* fbuf, const uint4* __restrict__ wfrag, int l,
    int wvu, int lane, int m16, int q2, v2f bc, unsigned (&X2)[4][4])
{
  floatx4 C[2][4];
  #pragma unroll
  for (int v = 0; v < 2; ++v)
    #pragma unroll
    for (int mt = 0; mt < 4; ++mt) C[v][mt] = (floatx4){0.f, 0.f, 0.f, 0.f};
  FragU B0, B1;
  {
    const uint4* wp0 = wfrag + (((l * 4 + 0) * 8 + 2 * wvu) << 6);
    B0.q = wp0[lane];  B1.q = wp0[64 + lane];
  }
  #pragma unroll
  for (int kt = 0; kt < 4; ++kt) {
    FragU nB0, nB1;
    if (kt < 3) {   // rotate-prefetch next kt's B under this kt's MFMAs
      const uint4* wpn = wfrag + (((l * 4 + kt + 1) * 8 + 2 * wvu) << 6);
      nB0.q = wpn[lane];  nB1.q = wpn[64 + lane];
    }
    #pragma unroll
    for (int mt = 0; mt < 4; ++mt) {
      const unsigned* fa = fbuf + (mt * 16 + m16) * 68 + kt * 16 + q2 * 4;
      FragU Ah;
      Ah.q = *(const uint4*)fa;
      C[0][mt] = __builtin_amdgcn_mfma_f32_16x16x32_bf16(Ah.v, B0.v, C[0][mt], 0, 0, 0);
      C[1][mt] = __builtin_amdgcn_mfma_f32_16x16x32_bf16(Ah.v, B1.v, C[1][mt], 0, 0, 0);
    }
    if (kt < 3) { B0 = nB0; B1 = nB1; }
  }
  #pragma unroll
  for (int mt = 0; mt < 4; ++mt)
    #pragma unroll
    for (int r = 0; r < 4; ++r) {
      v2f o; o.x = C[0][mt][r]; o.y = C[1][mt][r];
      o += bc;                                     // v_pk_add_f32
      o.x = fmaxf(o.x, 0.f); o.y = fmaxf(o.y, 0.f);  // v_pk_max_f32
      const v2f nx = unpk(X2[mt][r]) + o;          // residual in f32
      X2[mt][r] = cvt_pk_bf16(nx.x, nx.y);         // repack carrier
    }
}

__device__ __forceinline__ float pool_dot(const unsigned (&X2)[4][4], v2f wp)
{
  v2f p0 = (v2f){-3.4e38f, -3.4e38f}, p1 = p0;
  #pragma unroll
  for (int r = 0; r < 4; ++r) {
    const v2f a0 = unpk(X2[0][r]), a2 = unpk(X2[2][r]);
    const v2f a1 = unpk(X2[1][r]), a3 = unpk(X2[3][r]);
    p0.x = fmaxf(p0.x, fmaxf(a0.x, a2.x));
    p0.y = fmaxf(p0.y, fmaxf(a0.y, a2.y));
    p1.x = fmaxf(p1.x, fmaxf(a1.x, a3.x));
    p1.y = fmaxf(p1.y, fmaxf(a1.y, a3.y));
  }
  const v2f ps = (p0 + p1) * wp;
  return ps.x + ps.y;
}

// R9 structure + packed fp32 (R13) + bf16 A/B (R16/R17) + bounds floor
// (R19) + two-root stagger (R24) + R27: bf16-packed X2 carrier (-32 VGPR).
__global__ __launch_bounds__(256, 2)
void i2gnn_mfma(
    const int* __restrict__ x,
    const int* __restrict__ edge_attr,
    const int* __restrict__ tuplefeat,
    const float* __restrict__ emb_x,
    const float* __restrict__ emb_tf,
    const float* __restrict__ emb_ea,
    const float* __restrict__ lin32,
    const float* __restrict__ b_conv,
    const float* __restrict__ w_pred,
    const uint4* __restrict__ wfrag,
    float* __restrict__ out)
{
  __shared__ __align__(16) unsigned frag[2 * 64 * 68];   // 34816 B: bufA | bufB
  unsigned* bufA = frag;
  unsigned* bufB = frag + 4352;

  const int tid = threadIdx.x;
  const int wv = tid >> 6, lane = tid & 63;
  const int wvu = __builtin_amdgcn_readfirstlane(wv);   // SGPR wave index
  const int m16 = lane & 15, q2 = lane >> 4;
  const int pc = wvu * 16 + m16;       // logical pair-column this lane produces
  const int c0 = pc * 2;               // logical channels c0, c0+1

  const int iA = blockIdx.x * 2;       // two roots, same graph & 64-group
  const int iB = iA + 1;
  const int ibase = iA & ~63;
  const int ioA = iA & 63, ioB = iB & 63;
  const int g = iA >> 6;               // iB >> 6 identical (bit0 irrelevant)

  unsigned X2A[4][4], X2B[4][4];
  unsigned pkA[4] = {0u,0u,0u,0u}, pkB[4] = {0u,0u,0u,0u};
  tuple_init(iA, ibase, ioA, x, edge_attr, tuplefeat, emb_x, emb_tf, lin32,
             c0, q2, X2A, pkA);
  tuple_init(iB, ibase, ioB, x, edge_attr, tuplefeat, emb_x, emb_tf, lin32,
             c0, q2, X2B, pkB);

  // block-uniform attr words -> SGPRs once; all later unpack is SALU
  unsigned pkuA[4], pkuB[4];
  #pragma unroll
  for (int j = 0; j < 4; ++j) {
    pkuA[j] = (unsigned)__builtin_amdgcn_readfirstlane((int)pkA[j]);
    pkuB[j] = (unsigned)__builtin_amdgcn_readfirstlane((int)pkB[j]);
  }

  // prologue: fill bufA for layer 0
  msg_pack(X2A, pkuA, emb_ea, c0, q2, pc, bufA);
  __syncthreads();

  for (int l = 0; l < 5; ++l) {
    const v2f bc = ldv2(b_conv + l * EMB + c0);   // shared: same c0 both roots

    // ---- REGION 1: mfmaA(l) || msgB(l)+packB — independent chains; the
    //      scheduler fills mfmaA's LDS/MFMA latency with msgB VALU+loads ----
    mfma_resid(bufA, wfrag, l, wvu, lane, m16, q2, bc, X2A);
    msg_pack(X2B, pkuB, emb_ea, c0, q2, pc, bufB);
    __syncthreads();

    // ---- REGION 2: mfmaB(l) || msgA(l+1)+packA ----
    mfma_resid(bufB, wfrag, l, wvu, lane, m16, q2, bc, X2B);
    if (l < 4) {
      msg_pack(X2A, pkuA, emb_ea, c0, q2, pc, bufA);
      __syncthreads();
    }
  }

  // ---- pooling both roots, shared shuffle-reduce, single atomic ----
  const v2f wp = ldv2(w_pred + c0);
  float s = pool_dot(X2A, wp) + pool_dot(X2B, wp);
  #pragma unroll
  for (int off = 32; off; off >>= 1) s += __shfl_xor(s, off, 64);
  if (lane == 0) atomicAdd(out + g, s);
}

extern "C" void kernel_launch(void* const* d_in, const int* in_sizes, int n_in,
                              void* d_out, int out_size, void* d_ws, size_t ws_size,
                              hipStream_t stream) {
  const int*   x         = (const int*)d_in[0];
  const int*   edge_attr = (const int*)d_in[1];
  const int*   tuplefeat = (const int*)d_in[2];
  const float* emb_x     = (const float*)d_in[12];
  const float* emb_ea    = (const float*)d_in[13];
  const float* emb_tf    = (const float*)d_in[14];
  const float* w_ti      = (const float*)d_in[15];
  const float* b_ti      = (const float*)d_in[16];
  const float* w_conv    = (const float*)d_in[17];
  const float* b_conv    = (const float*)d_in[18];
  const float* w_pred    = (const float*)d_in[19];
  const float* b_pred    = (const float*)d_in[20];
  float* out = (float*)d_out;
  float* lin32 = (float*)d_ws;                               // 32*128 fp32 = 16 KB
  uint4* wfrag = (uint4*)((char*)d_ws + 32 * EMB * 4);       // 160 KB B-fragments

  hipLaunchKernelGGL(prep_kernel, dim3(53), dim3(512), 0, stream,
                     emb_x, w_ti, b_ti, w_conv, b_pred, lin32, wfrag, out);
  hipLaunchKernelGGL(i2gnn_mfma, dim3(2048), dim3(256), 0, stream,
                     x, edge_attr, tuplefeat, emb_x, emb_tf, emb_ea, lin32,
                     b_conv, w_pred, wfrag, out);
}

// Round 14
// 247.086 us; speedup vs baseline: 1.0503x; 1.0503x over previous
//
#include <hip/hip_runtime.h>
#include <hip/hip_bf16.h>

#define EMB 128

typedef __attribute__((ext_vector_type(8))) short short8;   // 8 bf16 (4 VGPRs)
typedef __attribute__((ext_vector_type(4))) float floatx4;  // MFMA C/D
typedef __attribute__((ext_vector_type(2))) float v2f;      // -> v_pk_fma_f32

// 26 valid (ok, di, ol) message combos: deltas = {1,2,-1,-2}, ol = ok+delta in [0,8)
static constexpr int OKv[26] = {0,0,1,1,1,2,2,2,2,3,3,3,3,4,4,4,4,5,5,5,5,6,6,6,7,7};
static constexpr int DIv[26] = {0,1,0,1,2,0,1,2,3,0,1,2,3,0,1,2,3,0,1,2,3,0,2,3,2,3};
static constexpr int OLv[26] = {1,2,2,3,0,3,4,1,0,4,5,2,1,5,6,3,2,6,7,4,3,7,5,4,6,5};

__device__ __forceinline__ v2f ldv2(const float* p) { return *(const v2f*)p; }

// round-to-nearest-even bf16 bits of x, kept in the TOP 16 bits (low 16 zero)
__device__ __forceinline__ unsigned bf16_rne_hi(float x) {
  unsigned u = __float_as_uint(x);
  return (u + 0x7FFFu + ((u >> 16) & 1u)) & 0xFFFF0000u;
}
// HW packed cvt: a -> low 16, b -> high 16 (v_cvt_pk_bf16_f32 on gfx950)
__device__ __forceinline__ unsigned cvt_pk_bf16(float a, float b) {
  __hip_bfloat162 h = __float22bfloat162_rn(make_float2(a, b));
  unsigned r; __builtin_memcpy(&r, &h, 4); return r;
}

union FragU { unsigned u[4]; uint4 q; short8 v; };

// LOGICAL CHANNEL PERMUTATION (R9-verified): MFMA C physical position
// (u, n=lane&15) carries logical channel L(u,n) = 2*((u>>1)*16 + n) + (u&1).
// Wave wv computes u in {2wv, 2wv+1} -> lane (wv, m16) holds the ADJACENT
// logical pair c0 = 2*(wv*16+m16), c0+1. Only wfrag bakes the permutation.
//
// SESSION NOTE (R28): R27 (bf16 X2 carrier) REGRESSED (+10%, VGPR stuck
// 128, VALUBusy 25->33: unpack on the serial chain, no residency gain) ->
// reverted. This round = R24 (session best, 155.5us main) + ONE clean A/B:
// s_setprio(1/0) around the staggered MFMA cluster. R24 dropped setprio
// untested; the stagger gives cross-block role diversity on each SIMD
// (block j in mfma-region, block k in msg-region) -> T5's enabling
// condition. GATE: dur > 158us -> setprio hurts the stagger; final kernel
// is R24 verbatim; declare structural plateau (latency-bound: ~10k issue
// cy/block vs ~42k wall at HW-pinned ~2 blocks/CU; all pipes <35%).
// Falsified: occupancy-floor attrs (R1/R6), LDS size/barrier scope (R7/R11),
// epilogue (R8/R9), bank conflicts (R11), B-prefetch-in-phase (R12), VALU
// width (R13), wave-PARALLEL widening (R14/R20), ea residency/LDS
// (R15/R19/R22/R23), asm-confounded sync (R18), addr scalarization +
// batched loads (R25/R26 null), bf16 X2 carrier (R27). Wins: bf16-A
// (R16, -17%), bf16-B (R17, -2%), bounds floor (R19, -6.5%), 1-barrier
// dbuf+B-hoist (R21, -3%), R22 (-4%), two-root stagger (R24, -4%).

// Fused prep, grid 53 x 512:
//  b 0..31  : lin32 row b (4-way f-split + LDS reduce)
//  b 32..51 : w_conv -> B-fragment bf16 pre-pack with permuted N (160 frags)
//  b 52     : out[g] = b_pred[0]
__global__ __launch_bounds__(512) void prep_kernel(
    const float* __restrict__ emb_x,
    const float* __restrict__ w_ti,
    const float* __restrict__ b_ti,
    const float* __restrict__ w_conv,
    const float* __restrict__ b_pred,
    float* __restrict__ lin32,
    uint4* __restrict__ wfrag,
    float* __restrict__ out) {
  const int b = blockIdx.x, tid = threadIdx.x;
  if (b < 32) {
    __shared__ float red[4][EMB];
    const int e = tid & 127, fh = tid >> 7;      // fh in [0,4)
    const float* xr = emb_x + b * EMB;
    float s = 0.f;
    #pragma unroll 8
    for (int f = fh * 32; f < fh * 32 + 32; ++f)
      s = fmaf(xr[f], w_ti[f * EMB + e], s);
    red[fh][e] = s;
    __syncthreads();
    if (fh == 0)
      lin32[b * EMB + e] =
          b_ti[e] + ((red[0][e] + red[1][e]) + (red[2][e] + red[3][e]));
  } else if (b < 52) {
    const int id   = (b - 32) * 512 + tid;   // 160 frags * 64 lanes = 10240
    const int lane = id & 63;
    const int f    = id >> 6;         // frag index: [l][kt][u]
    const int u    = f & 7;           // N-tile (physical)
    const int t    = (f >> 3) & 3;    // K-tile
    const int l    = f >> 5;          // layer
    const int q    = lane >> 4, n = lane & 15;
    const int cN   = 2 * ((u >> 1) * 16 + n) + (u & 1);   // logical out channel
    unsigned w[4] = {0u, 0u, 0u, 0u};
    #pragma unroll
    for (int j = 0; j < 8; ++j) {
      const int kk = t * 32 + q * 8 + j;    // logical in channel (canonical)
      const float val = w_conv[l * (EMB * EMB) + kk * EMB + cN];
      const unsigned bb = bf16_rne_hi(val);
      w[j >> 1] |= (j & 1) ? bb : (bb >> 16);
    }
    wfrag[id] = make_uint4(w[0], w[1], w[2], w[3]);
  } else {
    if (tid < 64) out[tid] = b_pred[0];
  }
}

// ---- per-root phase helpers (forceinline, all indexing compile-time) ----

__device__ __forceinline__ void tuple_init(
    int i, int ibase, int io,
    const int* __restrict__ x, const int* __restrict__ edge_attr,
    const int* __restrict__ tuplefeat,
    const float* __restrict__ emb_x, const float* __restrict__ emb_tf,
    const float* __restrict__ lin32,
    int c0, int q2, v2f (&X2)[4][4], unsigned (&pk)[4])
{
  #pragma unroll
  for (int m = 0; m < 26; ++m) {
    const int kg = ibase + ((io + OKv[m]) & 63);
    const unsigned a = (unsigned)edge_attr[(kg << 2) + DIv[m]];
    pk[m >> 3] |= a << ((m & 7) * 4);
  }
  const int xi = x[i];
  const v2f xe = ldv2(emb_x + xi * EMB + c0);
  v2f lj[2];
  #pragma unroll
  for (int ps = 0; ps < 2; ++ps) {
    const int jn = ibase + ((io + 2 * q2 + ps) & 63);
    lj[ps] = ldv2(lin32 + x[jn] * EMB + c0);
  }
  #pragma unroll
  for (int mt = 0; mt < 4; ++mt) {
    const int ps = mt & 1, kb = (mt >> 1) * 4;
    const int t0 = (i * 8 + 2 * q2 + ps) << 3;
    const v2f xl = xe * lj[ps];
    #pragma unroll
    for (int r = 0; r < 4; ++r) {
      const int2 tf2 = *(const int2*)(tuplefeat + 2 * (t0 + kb + r));
      const int row = (c0 < 64) ? tf2.x : tf2.y;   // c0,c0+1 in same half
      const v2f tf = ldv2(emb_tf + row * 64 + (c0 & 63));
      X2[mt][r] = xl * tf;
    }
  }
}

__device__ __forceinline__ void msg_pack(
    const v2f (&X2)[4][4], const unsigned (&pk)[4],
    const float* __restrict__ emb_ea,
    int c0, int q2, int pc, unsigned* fbuf)
{
  v2f acc[2][8];   // [ps][k]
  #pragma unroll
  for (int ps = 0; ps < 2; ++ps)
    #pragma unroll
    for (int k = 0; k < 8; ++k) acc[ps][k] = (v2f){0.f, 0.f};
  #pragma unroll
  for (int m = 0; m < 26; ++m) {
    const unsigned attr = (pk[m >> 3] >> ((m & 7) * 4)) & 15u;
    const v2f e = ldv2(emb_ea + attr * EMB + c0);
    const int ok = OKv[m], ol = OLv[m];
    const int mtb = 2 * (ol >> 2), rl = ol & 3;   // compile-time consts
    acc[0][ok] += X2[mtb + 0][rl] * e;            // v_pk_fma_f32
    acc[1][ok] += X2[mtb + 1][rl] * e;
  }
  #pragma unroll
  for (int ps = 0; ps < 2; ++ps)
    #pragma unroll
    for (int k = 0; k < 8; ++k) {
      const v2f a = acc[ps][k];
      const int row = (ps + 2 * (k >> 2)) * 16 + q2 * 4 + (k & 3);
      fbuf[row * 68 + pc] = cvt_pk_bf16(a.x, a.y);
    }
}

__device__ __forceinline__ void mfma_resid(
    const unsigned* fbuf, const uint4* __restrict__ wfrag, int l,
    int wv, int lane, int m16, int q2, v2f bc, v2f (&X2)[4][4])
{
  floatx4 C[2][4];
  #pragma unroll
  for (int v = 0; v < 2; ++v)
    #pragma unroll
    for (int mt = 0; mt < 4; ++mt) C[v][mt] = (floatx4){0.f, 0.f, 0.f, 0.f};
  FragU B0, B1;
  {
    const uint4* wp0 = wfrag + (((l * 4 + 0) * 8 + 2 * wv) << 6);
    B0.q = wp0[lane];  B1.q = wp0[64 + lane];
  }
  __builtin_amdgcn_s_setprio(1);   // R28: MFMA-region waves preferred on SIMD
  #pragma unroll
  for (int kt = 0; kt < 4; ++kt) {
    FragU nB0, nB1;
    if (kt < 3) {   // rotate-prefetch next kt's B under this kt's MFMAs
      const uint4* wpn = wfrag + (((l * 4 + kt + 1) * 8 + 2 * wv) << 6);
      nB0.q = wpn[lane];  nB1.q = wpn[64 + lane];
    }
    #pragma unroll
    for (int mt = 0; mt < 4; ++mt) {
      const unsigned* fa = fbuf + (mt * 16 + m16) * 68 + kt * 16 + q2 * 4;
      FragU Ah;
      Ah.q = *(const uint4*)fa;
      C[0][mt] = __builtin_amdgcn_mfma_f32_16x16x32_bf16(Ah.v, B0.v, C[0][mt], 0, 0, 0);
      C[1][mt] = __builtin_amdgcn_mfma_f32_16x16x32_bf16(Ah.v, B1.v, C[1][mt], 0, 0, 0);
    }
    if (kt < 3) { B0 = nB0; B1 = nB1; }
  }
  __builtin_amdgcn_s_setprio(0);
  #pragma unroll
  for (int mt = 0; mt < 4; ++mt)
    #pragma unroll
    for (int r = 0; r < 4; ++r) {
      v2f o; o.x = C[0][mt][r]; o.y = C[1][mt][r];
      o += bc;                                     // v_pk_add_f32
      o.x = fmaxf(o.x, 0.f); o.y = fmaxf(o.y, 0.f);  // v_pk_max_f32
      X2[mt][r] += o;
    }
}

__device__ __forceinline__ float pool_dot(const v2f (&X2)[4][4], v2f wp)
{
  v2f p0 = (v2f){-3.4e38f, -3.4e38f}, p1 = p0;
  #pragma unroll
  for (int r = 0; r < 4; ++r) {
    p0.x = fmaxf(p0.x, fmaxf(X2[0][r].x, X2[2][r].x));
    p0.y = fmaxf(p0.y, fmaxf(X2[0][r].y, X2[2][r].y));
    p1.x = fmaxf(p1.x, fmaxf(X2[1][r].x, X2[3][r].x));
    p1.y = fmaxf(p1.y, fmaxf(X2[1][r].y, X2[3][r].y));
  }
  const v2f ps = (p0 + p1) * wp;
  return ps.x + ps.y;
}

// R9 structure + packed fp32 (R13) + bf16 A/B (R16/R17) + bounds floor
// (R19) + two-root stagger (R24) + R28: setprio around staggered MFMA.
__global__ __launch_bounds__(256, 2)
void i2gnn_mfma(
    const int* __restrict__ x,
    const int* __restrict__ edge_attr,
    const int* __restrict__ tuplefeat,
    const float* __restrict__ emb_x,
    const float* __restrict__ emb_tf,
    const float* __restrict__ emb_ea,
    const float* __restrict__ lin32,
    const float* __restrict__ b_conv,
    const float* __restrict__ w_pred,
    const uint4* __restrict__ wfrag,
    float* __restrict__ out)
{
  __shared__ __align__(16) unsigned frag[2 * 64 * 68];   // 34816 B: bufA | bufB
  unsigned* bufA = frag;
  unsigned* bufB = frag + 4352;

  const int tid = threadIdx.x;
  const int wv = tid >> 6, lane = tid & 63;
  const int m16 = lane & 15, q2 = lane >> 4;
  const int pc = wv * 16 + m16;        // logical pair-column this lane produces
  const int c0 = pc * 2;               // logical channels c0, c0+1

  const int iA = blockIdx.x * 2;       // two roots, same graph & 64-group
  const int iB = iA + 1;
  const int ibase = iA & ~63;
  const int ioA = iA & 63, ioB = iB & 63;
  const int g = iA >> 6;               // iB >> 6 identical (bit0 irrelevant)

  v2f X2A[4][4], X2B[4][4];
  unsigned pkA[4] = {0u,0u,0u,0u}, pkB[4] = {0u,0u,0u,0u};
  tuple_init(iA, ibase, ioA, x, edge_attr, tuplefeat, emb_x, emb_tf, lin32,
             c0, q2, X2A, pkA);
  tuple_init(iB, ibase, ioB, x, edge_attr, tuplefeat, emb_x, emb_tf, lin32,
             c0, q2, X2B, pkB);

  // prologue: fill bufA for layer 0
  msg_pack(X2A, pkA, emb_ea, c0, q2, pc, bufA);
  __syncthreads();

  for (int l = 0; l < 5; ++l) {
    const v2f bc = ldv2(b_conv + l * EMB + c0);   // shared: same c0 both roots

    // ---- REGION 1: mfmaA(l) || msgB(l)+packB — independent chains; the
    //      scheduler fills mfmaA's LDS/MFMA latency with msgB VALU+loads ----
    mfma_resid(bufA, wfrag, l, wv, lane, m16, q2, bc, X2A);
    msg_pack(X2B, pkB, emb_ea, c0, q2, pc, bufB);
    __syncthreads();

    // ---- REGION 2: mfmaB(l) || msgA(l+1)+packA ----
    mfma_resid(bufB, wfrag, l, wv, lane, m16, q2, bc, X2B);
    if (l < 4) {
      msg_pack(X2A, pkA, emb_ea, c0, q2, pc, bufA);
      __syncthreads();
    }
  }

  // ---- pooling both roots, shared shuffle-reduce, single atomic ----
  const v2f wp = ldv2(w_pred + c0);
  float s = pool_dot(X2A, wp) + pool_dot(X2B, wp);
  #pragma unroll
  for (int off = 32; off; off >>= 1) s += __shfl_xor(s, off, 64);
  if (lane == 0) atomicAdd(out + g, s);
}

extern "C" void kernel_launch(void* const* d_in, const int* in_sizes, int n_in,
                              void* d_out, int out_size, void* d_ws, size_t ws_size,
                              hipStream_t stream) {
  const int*   x         = (const int*)d_in[0];
  const int*   edge_attr = (const int*)d_in[1];
  const int*   tuplefeat = (const int*)d_in[2];
  const float* emb_x     = (const float*)d_in[12];
  const float* emb_ea    = (const float*)d_in[13];
  const float* emb_tf    = (const float*)d_in[14];
  const float* w_ti      = (const float*)d_in[15];
  const float* b_ti      = (const float*)d_in[16];
  const float* w_conv    = (const float*)d_in[17];
  const float* b_conv    = (const float*)d_in[18];
  const float* w_pred    = (const float*)d_in[19];
  const float* b_pred    = (const float*)d_in[20];
  float* out = (float*)d_out;
  float* lin32 = (float*)d_ws;                               // 32*128 fp32 = 16 KB
  uint4* wfrag = (uint4*)((char*)d_ws + 32 * EMB * 4);       // 160 KB B-fragments

  hipLaunchKernelGGL(prep_kernel, dim3(53), dim3(512), 0, stream,
                     emb_x, w_ti, b_ti, w_conv, b_pred, lin32, wfrag, out);
  hipLaunchKernelGGL(i2gnn_mfma, dim3(2048), dim3(256), 0, stream,
                     x, edge_attr, tuplefeat, emb_x, emb_tf, emb_ea, lin32,
                     b_conv, w_pred, wfrag, out);
}

// Round 15
// 242.689 us; speedup vs baseline: 1.0693x; 1.0181x over previous
//
#include <hip/hip_runtime.h>
#include <hip/hip_bf16.h>

#define EMB 128

typedef __attribute__((ext_vector_type(8))) short short8;   // 8 bf16 (4 VGPRs)
typedef __attribute__((ext_vector_type(4))) float floatx4;  // MFMA C/D
typedef __attribute__((ext_vector_type(2))) float v2f;      // -> v_pk_fma_f32

// 26 valid (ok, di, ol) message combos: deltas = {1,2,-1,-2}, ol = ok+delta in [0,8)
static constexpr int OKv[26] = {0,0,1,1,1,2,2,2,2,3,3,3,3,4,4,4,4,5,5,5,5,6,6,6,7,7};
static constexpr int DIv[26] = {0,1,0,1,2,0,1,2,3,0,1,2,3,0,1,2,3,0,1,2,3,0,2,3,2,3};
static constexpr int OLv[26] = {1,2,2,3,0,3,4,1,0,4,5,2,1,5,6,3,2,6,7,4,3,7,5,4,6,5};

__device__ __forceinline__ v2f ldv2(const float* p) { return *(const v2f*)p; }

// round-to-nearest-even bf16 bits of x, kept in the TOP 16 bits (low 16 zero)
__device__ __forceinline__ unsigned bf16_rne_hi(float x) {
  unsigned u = __float_as_uint(x);
  return (u + 0x7FFFu + ((u >> 16) & 1u)) & 0xFFFF0000u;
}
// HW packed cvt: a -> low 16, b -> high 16 (v_cvt_pk_bf16_f32 on gfx950)
__device__ __forceinline__ unsigned cvt_pk_bf16(float a, float b) {
  __hip_bfloat162 h = __float22bfloat162_rn(make_float2(a, b));
  unsigned r; __builtin_memcpy(&r, &h, 4); return r;
}

union FragU { unsigned u[4]; uint4 q; short8 v; };

// LOGICAL CHANNEL PERMUTATION (R9-verified): MFMA C physical position
// (u, n=lane&15) carries logical channel L(u,n) = 2*((u>>1)*16 + n) + (u&1).
// Wave wv computes u in {2wv, 2wv+1} -> lane (wv, m16) holds the ADJACENT
// logical pair c0 = 2*(wv*16+m16), c0+1. Only wfrag bakes the permutation.
//
// SESSION FINAL (R29 = R24 verbatim, session best 155.5us main).
// Ledger 237 -> 155.5us main via: bf16-A (R16, -17%), bf16-B (R17, -2%),
// (256,2) bounds floor (R19, -6.5%), 1-barrier dbuf + B-hoist (R21, -3%),
// R22 (-4%), two-root in-wave stagger (R24, -4%). Structure is
// latency-bound at ~2 blocks/CU HW residency, all pipes <35% — a
// structural plateau, not a counter roofline.
// Falsified levers: occupancy-floor attrs (R1/R6), LDS size/barrier scope
// (R7/R11), epilogue (R8/R9), bank conflicts (R11), B-prefetch-in-phase
// (R12), VALU width (R13), wave-PARALLEL widening (R14/R20), ea register/
// LDS residency (R15/R19/R22/R23), asm-confounded sync (R18), addr
// scalarization + batched loads (R25/R26), bf16 X2 carrier (R27, +10%),
// setprio on the stagger (R28, +3%: priority boost starves the msg-region
// waves that fill MFMA stalls — T5 harmful once the stagger exists).

// Fused prep, grid 53 x 512:
//  b 0..31  : lin32 row b (4-way f-split + LDS reduce)
//  b 32..51 : w_conv -> B-fragment bf16 pre-pack with permuted N (160 frags)
//  b 52     : out[g] = b_pred[0]
__global__ __launch_bounds__(512) void prep_kernel(
    const float* __restrict__ emb_x,
    const float* __restrict__ w_ti,
    const float* __restrict__ b_ti,
    const float* __restrict__ w_conv,
    const float* __restrict__ b_pred,
    float* __restrict__ lin32,
    uint4* __restrict__ wfrag,
    float* __restrict__ out) {
  const int b = blockIdx.x, tid = threadIdx.x;
  if (b < 32) {
    __shared__ float red[4][EMB];
    const int e = tid & 127, fh = tid >> 7;      // fh in [0,4)
    const float* xr = emb_x + b * EMB;
    float s = 0.f;
    #pragma unroll 8
    for (int f = fh * 32; f < fh * 32 + 32; ++f)
      s = fmaf(xr[f], w_ti[f * EMB + e], s);
    red[fh][e] = s;
    __syncthreads();
    if (fh == 0)
      lin32[b * EMB + e] =
          b_ti[e] + ((red[0][e] + red[1][e]) + (red[2][e] + red[3][e]));
  } else if (b < 52) {
    const int id   = (b - 32) * 512 + tid;   // 160 frags * 64 lanes = 10240
    const int lane = id & 63;
    const int f    = id >> 6;         // frag index: [l][kt][u]
    const int u    = f & 7;           // N-tile (physical)
    const int t    = (f >> 3) & 3;    // K-tile
    const int l    = f >> 5;          // layer
    const int q    = lane >> 4, n = lane & 15;
    const int cN   = 2 * ((u >> 1) * 16 + n) + (u & 1);   // logical out channel
    unsigned w[4] = {0u, 0u, 0u, 0u};
    #pragma unroll
    for (int j = 0; j < 8; ++j) {
      const int kk = t * 32 + q * 8 + j;    // logical in channel (canonical)
      const float val = w_conv[l * (EMB * EMB) + kk * EMB + cN];
      const unsigned bb = bf16_rne_hi(val);
      w[j >> 1] |= (j & 1) ? bb : (bb >> 16);
    }
    wfrag[id] = make_uint4(w[0], w[1], w[2], w[3]);
  } else {
    if (tid < 64) out[tid] = b_pred[0];
  }
}

// ---- per-root phase helpers (forceinline, all indexing compile-time) ----

__device__ __forceinline__ void tuple_init(
    int i, int ibase, int io,
    const int* __restrict__ x, const int* __restrict__ edge_attr,
    const int* __restrict__ tuplefeat,
    const float* __restrict__ emb_x, const float* __restrict__ emb_tf,
    const float* __restrict__ lin32,
    int c0, int q2, v2f (&X2)[4][4], unsigned (&pk)[4])
{
  #pragma unroll
  for (int m = 0; m < 26; ++m) {
    const int kg = ibase + ((io + OKv[m]) & 63);
    const unsigned a = (unsigned)edge_attr[(kg << 2) + DIv[m]];
    pk[m >> 3] |= a << ((m & 7) * 4);
  }
  const int xi = x[i];
  const v2f xe = ldv2(emb_x + xi * EMB + c0);
  v2f lj[2];
  #pragma unroll
  for (int ps = 0; ps < 2; ++ps) {
    const int jn = ibase + ((io + 2 * q2 + ps) & 63);
    lj[ps] = ldv2(lin32 + x[jn] * EMB + c0);
  }
  #pragma unroll
  for (int mt = 0; mt < 4; ++mt) {
    const int ps = mt & 1, kb = (mt >> 1) * 4;
    const int t0 = (i * 8 + 2 * q2 + ps) << 3;
    const v2f xl = xe * lj[ps];
    #pragma unroll
    for (int r = 0; r < 4; ++r) {
      const int2 tf2 = *(const int2*)(tuplefeat + 2 * (t0 + kb + r));
      const int row = (c0 < 64) ? tf2.x : tf2.y;   // c0,c0+1 in same half
      const v2f tf = ldv2(emb_tf + row * 64 + (c0 & 63));
      X2[mt][r] = xl * tf;
    }
  }
}

__device__ __forceinline__ void msg_pack(
    const v2f (&X2)[4][4], const unsigned (&pk)[4],
    const float* __restrict__ emb_ea,
    int c0, int q2, int pc, unsigned* fbuf)
{
  v2f acc[2][8];   // [ps][k]
  #pragma unroll
  for (int ps = 0; ps < 2; ++ps)
    #pragma unroll
    for (int k = 0; k < 8; ++k) acc[ps][k] = (v2f){0.f, 0.f};
  #pragma unroll
  for (int m = 0; m < 26; ++m) {
    const unsigned attr = (pk[m >> 3] >> ((m & 7) * 4)) & 15u;
    const v2f e = ldv2(emb_ea + attr * EMB + c0);
    const int ok = OKv[m], ol = OLv[m];
    const int mtb = 2 * (ol >> 2), rl = ol & 3;   // compile-time consts
    acc[0][ok] += X2[mtb + 0][rl] * e;            // v_pk_fma_f32
    acc[1][ok] += X2[mtb + 1][rl] * e;
  }
  #pragma unroll
  for (int ps = 0; ps < 2; ++ps)
    #pragma unroll
    for (int k = 0; k < 8; ++k) {
      const v2f a = acc[ps][k];
      const int row = (ps + 2 * (k >> 2)) * 16 + q2 * 4 + (k & 3);
      fbuf[row * 68 + pc] = cvt_pk_bf16(a.x, a.y);
    }
}

__device__ __forceinline__ void mfma_resid(
    const unsigned* fbuf, const uint4* __restrict__ wfrag, int l,
    int wv, int lane, int m16, int q2, v2f bc, v2f (&X2)[4][4])
{
  floatx4 C[2][4];
  #pragma unroll
  for (int v = 0; v < 2; ++v)
    #pragma unroll
    for (int mt = 0; mt < 4; ++mt) C[v][mt] = (floatx4){0.f, 0.f, 0.f, 0.f};
  FragU B0, B1;
  {
    const uint4* wp0 = wfrag + (((l * 4 + 0) * 8 + 2 * wv) << 6);
    B0.q = wp0[lane];  B1.q = wp0[64 + lane];
  }
  #pragma unroll
  for (int kt = 0; kt < 4; ++kt) {
    FragU nB0, nB1;
    if (kt < 3) {   // rotate-prefetch next kt's B under this kt's MFMAs
      const uint4* wpn = wfrag + (((l * 4 + kt + 1) * 8 + 2 * wv) << 6);
      nB0.q = wpn[lane];  nB1.q = wpn[64 + lane];
    }
    #pragma unroll
    for (int mt = 0; mt < 4; ++mt) {
      const unsigned* fa = fbuf + (mt * 16 + m16) * 68 + kt * 16 + q2 * 4;
      FragU Ah;
      Ah.q = *(const uint4*)fa;
      C[0][mt] = __builtin_amdgcn_mfma_f32_16x16x32_bf16(Ah.v, B0.v, C[0][mt], 0, 0, 0);
      C[1][mt] = __builtin_amdgcn_mfma_f32_16x16x32_bf16(Ah.v, B1.v, C[1][mt], 0, 0, 0);
    }
    if (kt < 3) { B0 = nB0; B1 = nB1; }
  }
  #pragma unroll
  for (int mt = 0; mt < 4; ++mt)
    #pragma unroll
    for (int r = 0; r < 4; ++r) {
      v2f o; o.x = C[0][mt][r]; o.y = C[1][mt][r];
      o += bc;                                     // v_pk_add_f32
      o.x = fmaxf(o.x, 0.f); o.y = fmaxf(o.y, 0.f);  // v_pk_max_f32
      X2[mt][r] += o;
    }
}

__device__ __forceinline__ float pool_dot(const v2f (&X2)[4][4], v2f wp)
{
  v2f p0 = (v2f){-3.4e38f, -3.4e38f}, p1 = p0;
  #pragma unroll
  for (int r = 0; r < 4; ++r) {
    p0.x = fmaxf(p0.x, fmaxf(X2[0][r].x, X2[2][r].x));
    p0.y = fmaxf(p0.y, fmaxf(X2[0][r].y, X2[2][r].y));
    p1.x = fmaxf(p1.x, fmaxf(X2[1][r].x, X2[3][r].x));
    p1.y = fmaxf(p1.y, fmaxf(X2[1][r].y, X2[3][r].y));
  }
  const v2f ps = (p0 + p1) * wp;
  return ps.x + ps.y;
}

// R9 structure + packed fp32 (R13) + bf16 A/B (R16/R17) + bounds floor
// (R19) + two-root in-wave stagger (R24). No setprio (R28: harmful here).
__global__ __launch_bounds__(256, 2)
void i2gnn_mfma(
    const int* __restrict__ x,
    const int* __restrict__ edge_attr,
    const int* __restrict__ tuplefeat,
    const float* __restrict__ emb_x,
    const float* __restrict__ emb_tf,
    const float* __restrict__ emb_ea,
    const float* __restrict__ lin32,
    const float* __restrict__ b_conv,
    const float* __restrict__ w_pred,
    const uint4* __restrict__ wfrag,
    float* __restrict__ out)
{
  __shared__ __align__(16) unsigned frag[2 * 64 * 68];   // 34816 B: bufA | bufB
  unsigned* bufA = frag;
  unsigned* bufB = frag + 4352;

  const int tid = threadIdx.x;
  const int wv = tid >> 6, lane = tid & 63;
  const int m16 = lane & 15, q2 = lane >> 4;
  const int pc = wv * 16 + m16;        // logical pair-column this lane produces
  const int c0 = pc * 2;               // logical channels c0, c0+1

  const int iA = blockIdx.x * 2;       // two roots, same graph & 64-group
  const int iB = iA + 1;
  const int ibase = iA & ~63;
  const int ioA = iA & 63, ioB = iB & 63;
  const int g = iA >> 6;               // iB >> 6 identical (bit0 irrelevant)

  v2f X2A[4][4], X2B[4][4];
  unsigned pkA[4] = {0u,0u,0u,0u}, pkB[4] = {0u,0u,0u,0u};
  tuple_init(iA, ibase, ioA, x, edge_attr, tuplefeat, emb_x, emb_tf, lin32,
             c0, q2, X2A, pkA);
  tuple_init(iB, ibase, ioB, x, edge_attr, tuplefeat, emb_x, emb_tf, lin32,
             c0, q2, X2B, pkB);

  // prologue: fill bufA for layer 0
  msg_pack(X2A, pkA, emb_ea, c0, q2, pc, bufA);
  __syncthreads();

  for (int l = 0; l < 5; ++l) {
    const v2f bc = ldv2(b_conv + l * EMB + c0);   // shared: same c0 both roots

    // ---- REGION 1: mfmaA(l) || msgB(l)+packB — independent chains; the
    //      scheduler fills mfmaA's LDS/MFMA latency with msgB VALU+loads ----
    mfma_resid(bufA, wfrag, l, wv, lane, m16, q2, bc, X2A);
    msg_pack(X2B, pkB, emb_ea, c0, q2, pc, bufB);
    __syncthreads();

    // ---- REGION 2: mfmaB(l) || msgA(l+1)+packA ----
    mfma_resid(bufB, wfrag, l, wv, lane, m16, q2, bc, X2B);
    if (l < 4) {
      msg_pack(X2A, pkA, emb_ea, c0, q2, pc, bufA);
      __syncthreads();
    }
  }

  // ---- pooling both roots, shared shuffle-reduce, single atomic ----
  const v2f wp = ldv2(w_pred + c0);
  float s = pool_dot(X2A, wp) + pool_dot(X2B, wp);
  #pragma unroll
  for (int off = 32; off; off >>= 1) s += __shfl_xor(s, off, 64);
  if (lane == 0) atomicAdd(out + g, s);
}

extern "C" void kernel_launch(void* const* d_in, const int* in_sizes, int n_in,
                              void* d_out, int out_size, void* d_ws, size_t ws_size,
                              hipStream_t stream) {
  const int*   x         = (const int*)d_in[0];
  const int*   edge_attr = (const int*)d_in[1];
  const int*   tuplefeat = (const int*)d_in[2];
  const float* emb_x     = (const float*)d_in[12];
  const float* emb_ea    = (const float*)d_in[13];
  const float* emb_tf    = (const float*)d_in[14];
  const float* w_ti      = (const float*)d_in[15];
  const float* b_ti      = (const float*)d_in[16];
  const float* w_conv    = (const float*)d_in[17];
  const float* b_conv    = (const float*)d_in[18];
  const float* w_pred    = (const float*)d_in[19];
  const float* b_pred    = (const float*)d_in[20];
  float* out = (float*)d_out;
  float* lin32 = (float*)d_ws;                               // 32*128 fp32 = 16 KB
  uint4* wfrag = (uint4*)((char*)d_ws + 32 * EMB * 4);       // 160 KB B-fragments

  hipLaunchKernelGGL(prep_kernel, dim3(53), dim3(512), 0, stream,
                     emb_x, w_ti, b_ti, w_conv, b_pred, lin32, wfrag, out);
  hipLaunchKernelGGL(i2gnn_mfma, dim3(2048), dim3(256), 0, stream,
                     x, edge_attr, tuplefeat, emb_x, emb_tf, emb_ea, lin32,
                     b_conv, w_pred, wfrag, out);
}